// Round 14
// baseline (157.766 us; speedup 1.0000x reference)
//
#include <hip/hip_runtime.h>
#include <hip/hip_bf16.h>

#define BATCH 8
#define NTOK 4096      // H*W per batch
#define CH 256
#define CF 32
#define KVBLK 128
#define NITER (NTOK / KVBLK)

typedef float v4f __attribute__((ext_vector_type(4)));
typedef float v16f __attribute__((ext_vector_type(16)));
typedef short v8s __attribute__((ext_vector_type(8)));

static __device__ __forceinline__ ushort f2bf(float f) {
    union { float f; uint u; } v; v.f = f;
    uint u = v.u;
    uint r = (u + 0x7fffu + ((u >> 16) & 1u)) >> 16;   // round-nearest-even
    return (ushort)r;
}

static __device__ __forceinline__ uint cvt_pk(float lo, float hi) {
    uint r;
    asm("v_cvt_pk_bf16_f32 %0, %1, %2" : "=v"(r) : "v"(lo), "v"(hi));
    return r;
}

// two-output lane swap across lane<32 / lane>=32
static __device__ __forceinline__ void plswap(uint& a, uint& b) {
    asm("v_permlane32_swap_b32 %0, %1" : "+v"(a), "+v"(b));
}

static __device__ __forceinline__ void gload16(const void* g, void* l) {
    __builtin_amdgcn_global_load_lds(
        (const __attribute__((address_space(1))) unsigned int*)g,
        (__attribute__((address_space(3))) unsigned int*)l, 16, 0, 0);
}

#define MFMA16(a, b, c) __builtin_amdgcn_mfma_f32_16x16x32_bf16(a, b, c, 0, 0, 0)
#define MFMA32(a, b, c) __builtin_amdgcn_mfma_f32_32x32x16_bf16(a, b, c, 0, 0, 0)

// ---------------------------------------------------------------------------
// Kernel 1: transpose + cast weights to bf16 via LDS tiles (coalesced both ways)
// ---------------------------------------------------------------------------
__global__ __launch_bounds__(256) void prep_weights(
    const float* __restrict__ kf, const float* __restrict__ kg,
    const float* __restrict__ kh,
    ushort* __restrict__ wfT, ushort* __restrict__ wgT, ushort* __restrict__ whT) {
    __shared__ float tile[64][33];
    int bid = blockIdx.x;
    const float* src; ushort* dst; int cols, k0, c0;
    if (bid < 32)      { src = kh; dst = whT; cols = 256; k0 = (bid >> 3) * 64; c0 = (bid & 7) * 32; }
    else if (bid < 36) { src = kf; dst = wfT; cols = 32;  k0 = (bid - 32) * 64; c0 = 0; }
    else               { src = kg; dst = wgT; cols = 32;  k0 = (bid - 36) * 64; c0 = 0; }
    int t = threadIdx.x;
    int kr = t >> 2, cb = (t & 3) * 8;
#pragma unroll
    for (int j = 0; j < 8; ++j) tile[kr][cb + j] = src[(size_t)(k0 + kr) * cols + c0 + cb + j];
    __syncthreads();
    int c = t >> 3, kc = (t & 7) * 8;
    ushort tmp[8];
#pragma unroll
    for (int j = 0; j < 8; ++j) tmp[j] = f2bf(tile[kc + j][c]);
    *(uint4*)(dst + (size_t)(c0 + c) * CH + k0 + kc) = *(uint4*)tmp;
}

// ---------------------------------------------------------------------------
// Kernel 2: fused projections (f, g, hT) — one x read; weights pipelined;
// epilogue via LDS bounce -> 16B coalesced stores (was 24 scalar 2B stores).
// ---------------------------------------------------------------------------
__global__ __launch_bounds__(512) void proj_all(
    const float* __restrict__ x, const ushort* __restrict__ wfT,
    const ushort* __restrict__ wgT, const ushort* __restrict__ whT,
    const float* __restrict__ bf, const float* __restrict__ bg,
    const float* __restrict__ bh,
    ushort* __restrict__ fo, ushort* __restrict__ go, ushort* __restrict__ hT) {
    __shared__ __align__(16) ushort xl[64 * 256];   // 32 KB, 16B-chunk swizzle ^(n&7)
    __shared__ __align__(16) float xlf[128 * 66];   // 33 KB epilogue bounce
    int tid = threadIdx.x;
    int lane = tid & 63, w = tid >> 6;
    int row = lane & 15, g4 = lane >> 4;
    int n0 = blockIdx.x * 64;

#pragma unroll
    for (int i = 0; i < 4; ++i) {
        int id = i * 512 + tid;          // 2048 chunks of 16 B
        int n = id >> 5, cc = id & 31;
        const float* xp = x + (size_t)(n0 + n) * CH + cc * 8;
        float4 a0 = ((const float4*)xp)[0], a1 = ((const float4*)xp)[1];
        uint4 pv;
        pv.x = cvt_pk(a0.x, a0.y); pv.y = cvt_pk(a0.z, a0.w);
        pv.z = cvt_pk(a1.x, a1.y); pv.w = cvt_pk(a1.z, a1.w);
        *(uint4*)((char*)xl + n * 512 + ((cc ^ (n & 7)) << 4)) = pv;
    }

    int c0 = w * 32;
    int myNt = w & 3;
    const ushort* wpT = (w < 4) ? wfT : wgT;

    // prefetch ks=0 weight fragments (L2)
    v8s wh0 = *(const v8s*)(whT + (size_t)(c0 + row) * CH + g4 * 8);
    v8s wh1 = *(const v8s*)(whT + (size_t)(c0 + 16 + row) * CH + g4 * 8);
    v8s wp0 = *(const v8s*)(wpT + (size_t)row * CH + g4 * 8);
    v8s wp1 = *(const v8s*)(wpT + (size_t)(16 + row) * CH + g4 * 8);

    __syncthreads();

    v4f acch[2][4] = {};
    v4f accp[2] = {};
    for (int ks = 0; ks < 8; ++ks) {
        v8s nh0 = {}, nh1 = {}, np0 = {}, np1 = {};
        if (ks < 7) {
            int kk = (ks + 1) * 32 + g4 * 8;
            nh0 = *(const v8s*)(whT + (size_t)(c0 + row) * CH + kk);
            nh1 = *(const v8s*)(whT + (size_t)(c0 + 16 + row) * CH + kk);
            np0 = *(const v8s*)(wpT + (size_t)row * CH + kk);
            np1 = *(const v8s*)(wpT + (size_t)(16 + row) * CH + kk);
        }
        v8s xf[4];
#pragma unroll
        for (int nt = 0; nt < 4; ++nt) {
            int n = nt * 16 + row;
            int ch = (ks * 4 + g4) ^ (n & 7);
            xf[nt] = *(const v8s*)((char*)xl + n * 512 + (ch << 4));
        }
#pragma unroll
        for (int nt = 0; nt < 4; ++nt) {
            acch[0][nt] = MFMA16(wh0, xf[nt], acch[0][nt]);
            acch[1][nt] = MFMA16(wh1, xf[nt], acch[1][nt]);
        }
        accp[0] = MFMA16(xf[myNt], wp0, accp[0]);
        accp[1] = MFMA16(xf[myNt], wp1, accp[1]);
        wh0 = nh0; wh1 = nh1; wp0 = np0; wp1 = np1;
    }

    int batch = n0 >> 12;
    int nn0 = n0 & (NTOK - 1);
    ushort* hTb = hT + (size_t)batch * CH * NTOK;
    int sel = w >> 2;   // 0 = f, 1 = g
    const float* bp = (sel == 0) ? bf : bg;

    // ---- phase A: fo/go via LDS bounce (write f32, read 8-wide, uint4 store) ----
#pragma unroll
    for (int ct = 0; ct < 2; ++ct)
#pragma unroll
        for (int r = 0; r < 4; ++r) {
            int nl = myNt * 16 + g4 * 4 + r;
            int cf = ct * 16 + row;
            xlf[sel * 2048 + nl * 32 + cf] = accp[ct][r] + bp[cf];
        }
    __syncthreads();
    {
        int s_ = tid >> 8, n_ = (tid >> 2) & 63, q_ = tid & 3;
        const float* src = &xlf[s_ * 2048 + n_ * 32 + q_ * 8];
        uint4 pv;
        pv.x = cvt_pk(src[0], src[1]); pv.y = cvt_pk(src[2], src[3]);
        pv.z = cvt_pk(src[4], src[5]); pv.w = cvt_pk(src[6], src[7]);
        ushort* dst = ((s_ == 0) ? fo : go) + (size_t)(n0 + n_) * CF + q_ * 8;
        *(uint4*)dst = pv;
    }

    // ---- phase B: hT via LDS bounce, 2 rounds (ct), 16B coalesced stores ----
#pragma unroll
    for (int ct = 0; ct < 2; ++ct) {
        __syncthreads();   // WAR on xlf
#pragma unroll
        for (int r = 0; r < 4; ++r) {
            int ci = w * 16 + g4 * 4 + r;       // 0..127
            int c = w * 32 + ct * 16 + g4 * 4 + r;
            float bias = bh[c];
#pragma unroll
            for (int nt = 0; nt < 4; ++nt)
                xlf[ci * 66 + nt * 16 + row] = acch[ct][nt][r] + bias;
        }
        __syncthreads();
        {
            int ci = tid >> 2, nc = tid & 3;
            const float* src = &xlf[ci * 66 + nc * 16];
            uint4 p0, p1;
            p0.x = cvt_pk(src[0], src[1]);   p0.y = cvt_pk(src[2], src[3]);
            p0.z = cvt_pk(src[4], src[5]);   p0.w = cvt_pk(src[6], src[7]);
            p1.x = cvt_pk(src[8], src[9]);   p1.y = cvt_pk(src[10], src[11]);
            p1.z = cvt_pk(src[12], src[13]); p1.w = cvt_pk(src[14], src[15]);
            int c = (ci >> 4) * 32 + ct * 16 + (ci & 15);
            ushort* dst = hTb + (size_t)c * NTOK + nn0 + nc * 16;
            *(uint4*)dst = p0;
            *(uint4*)(dst + 8) = p1;
        }
    }
}

// ---------------------------------------------------------------------------
// Kernel 3: flash attention.  KVBLK=128: 32 iters, half the barriers.
// 512 thr = 8 waves = 4 qg(32q) x 2 kh(64key); grid 256 (1 block/CU).
// Per iter: 8 V gloads + 4 K reg-loads -> counted vmcnt(12).  K in registers;
// no-max softmax P = exp(s-24); in-register P pack; kh merge via LDS epilogue.
// ---------------------------------------------------------------------------
__global__ __launch_bounds__(512, 1) void flash_attn(
    const ushort* __restrict__ fbuf, const ushort* __restrict__ gbuf,
    const ushort* __restrict__ hT, const float* __restrict__ x,
    const float* __restrict__ gamma, float* __restrict__ out) {
    __shared__ __align__(16) ushort lds_v[2][32768];   // 128 KB (256c x 128k each)
    __shared__ float lsx[4][32];                       // pair lsum exchange

    int tid = threadIdx.x;
    int lane = tid & 63, w = tid >> 6;
    int row31 = lane & 31, h = lane >> 5;
    int batch = blockIdx.x & 7;
    int qg = w >> 1, kh = w & 1;
    int q0 = (blockIdx.x >> 3) * 128 + qg * 32;

    const ushort* fB = fbuf + (size_t)batch * NTOK * CF;
    const ushort* gB = gbuf + (size_t)batch * NTOK * CF;
    const ushort* hB = hT + (size_t)batch * CH * NTOK;

    // ---- V staging: 4096 chunks of 16B; thread covers 8 (c = i*32 + tid>>4) ----
    int crow = tid >> 4;                                  // 0..31
    int koffe = ((tid & 15) ^ (crow & 15)) << 3;          // pre-swizzled key offset
    const ushort* vpb = hB + (size_t)crow * NTOK + koffe; // + i*32*NTOK per chunk

#define STAGE(buf) do {                                                    \
        _Pragma("unroll")                                                  \
        for (int i_ = 0; i_ < 8; ++i_)                                     \
            gload16(vpb + (size_t)(i_ * 32) * NTOK,                        \
                    (char*)&lds_v[buf][0] + (i_ * 512 + tid) * 16);        \
    } while (0)

    // K A-frag source: rows kh*64 + kt*32 + row31, cols h*8 (+16 for cf-half 1)
    const ushort* kp = fB + (size_t)(kh * 64 + row31) * CF + h * 8;

    // hoisted V LDS offsets: ch = kh*8 + (kt*2+j)*2 + h, phys = ch ^ (row31&15)
    int voff[2][2];
#pragma unroll
    for (int kt = 0; kt < 2; ++kt)
#pragma unroll
        for (int j = 0; j < 2; ++j) {
            int ch = kh * 8 + (kt * 2 + j) * 2 + h;
            voff[kt][j] = row31 * 256 + ((ch ^ (row31 & 15)) << 4);
        }

    // Q^T B-frags
    v8s bq[2];
    bq[0] = *(const v8s*)(gB + (size_t)(q0 + row31) * CF + h * 8);
    bq[1] = *(const v8s*)(gB + (size_t)(q0 + row31) * CF + 16 + h * 8);

    float lsum = 0.f;
    v16f acc[8] = {};   // O partial: 32 q x 256 c
    const v16f z16 = {};

    // prologue: K(0) + V(0) in flight (12 outstanding)
    v8s k00 = *(const v8s*)kp;
    v8s k01 = *(const v8s*)(kp + 16);
    v8s k10 = *(const v8s*)(kp + 32 * CF);
    v8s k11 = *(const v8s*)(kp + 32 * CF + 16);
    kp += KVBLK * CF;
    STAGE(0); vpb += KVBLK;

    for (int t = 0; t < NITER; ++t) {
        int cur = t & 1;
        __builtin_amdgcn_s_barrier();           // B1: WAR-protect buf being restaged
        v8s n00 = {}, n01 = {}, n10 = {}, n11 = {};
        if (t + 1 < NITER) {
            STAGE(cur ^ 1); vpb += KVBLK;
            n00 = *(const v8s*)kp;
            n01 = *(const v8s*)(kp + 16);
            n10 = *(const v8s*)(kp + 32 * CF);
            n11 = *(const v8s*)(kp + 32 * CF + 16);
            kp += KVBLK * CF;
            asm volatile("s_waitcnt vmcnt(12)" ::: "memory");  // tile-t landed
        } else {
            asm volatile("s_waitcnt vmcnt(0)" ::: "memory");
        }
        __builtin_amdgcn_s_barrier();           // B2: all waves' tile-t data ready

        const char* vb = (const char*)&lds_v[cur][0];

        // ---- S = K_half * Q^T : 2 key-tiles of 32 ----
        v16f s0, s1;
        s0 = MFMA32(k00, bq[0], z16); s0 = MFMA32(k01, bq[1], s0);
        s1 = MFMA32(k10, bq[0], z16); s1 = MFMA32(k11, bq[1], s1);

        // ---- no-max softmax ----
        float psum = 0.f;
#pragma unroll
        for (int r = 0; r < 16; ++r) {
            s0[r] = __builtin_amdgcn_exp2f(s0[r] * 1.44269504f - 34.6246924f);
            s1[r] = __builtin_amdgcn_exp2f(s1[r] * 1.44269504f - 34.6246924f);
            psum += s0[r] + s1[r];
        }
        psum += __shfl_xor(psum, 32);
        lsum += psum;

        // ---- pack + PV, per key-tile x j-half ----
        __builtin_amdgcn_s_setprio(1);
#pragma unroll
        for (int kt = 0; kt < 2; ++kt)
#pragma unroll
            for (int j = 0; j < 2; ++j) {
                int R = j * 8;
                uint a0, a1, b0, b1;
                if (kt == 0) {
                    a0 = cvt_pk(s0[R + 0], s0[R + 1]); a1 = cvt_pk(s0[R + 2], s0[R + 3]);
                    b0 = cvt_pk(s0[R + 4], s0[R + 5]); b1 = cvt_pk(s0[R + 6], s0[R + 7]);
                } else {
                    a0 = cvt_pk(s1[R + 0], s1[R + 1]); a1 = cvt_pk(s1[R + 2], s1[R + 3]);
                    b0 = cvt_pk(s1[R + 4], s1[R + 5]); b1 = cvt_pk(s1[R + 6], s1[R + 7]);
                }
                plswap(a0, b0);
                plswap(a1, b1);
                union { v8s v; uint u[4]; } pu;
                pu.u[0] = a0; pu.u[1] = a1; pu.u[2] = b0; pu.u[3] = b1;
#pragma unroll
                for (int ct = 0; ct < 8; ++ct) {
                    v8s bv = *(const v8s*)(vb + voff[kt][j] + ct * 8192);
                    acc[ct] = MFMA32(pu.v, bv, acc[ct]);
                }
            }
        __builtin_amdgcn_s_setprio(0);
        k00 = n00; k01 = n01; k10 = n10; k11 = n11;
    }
#undef STAGE

    // ---- epilogue: merge kh pair (plain add), out = gamma*O/lsum + x ----
    // last compute read lds_v[1]; mbuf = lds_v[0] safe to overwrite.
    float gm = gamma[0];
    float* mbuf = (float*)&lds_v[0][0];
    int p = qg;
    if (kh == 1) {
        lsx[p][row31] = lsum;
#pragma unroll
        for (int ct = 0; ct < 4; ++ct)
#pragma unroll
            for (int r = 0; r < 16; ++r) {
                int qrow = (r & 3) + 8 * (r >> 2) + 4 * h;
                mbuf[p * 4096 + qrow * 128 + ct * 32 + row31] = acc[ct][r];
            }
    }
    __syncthreads();
    float linv = 0.f;
    if (kh == 0) {
        float ltot = lsum + lsx[p][row31];
        linv = 1.0f / ltot;
#pragma unroll
        for (int ct = 0; ct < 4; ++ct)
#pragma unroll
            for (int r = 0; r < 16; ++r) {
                int qrow = (r & 3) + 8 * (r >> 2) + 4 * h;
                float li = __shfl(linv, qrow);
                float val = acc[ct][r] + mbuf[p * 4096 + qrow * 128 + ct * 32 + row31];
                size_t idx = ((size_t)batch * NTOK + q0 + qrow) * CH + ct * 32 + row31;
                out[idx] = gm * (val * li) + x[idx];
            }
    }
    __syncthreads();
    if (kh == 1) {
#pragma unroll
        for (int ct = 4; ct < 8; ++ct)
#pragma unroll
            for (int r = 0; r < 16; ++r) {
                int qrow = (r & 3) + 8 * (r >> 2) + 4 * h;
                mbuf[p * 4096 + qrow * 128 + (ct - 4) * 32 + row31] = acc[ct][r];
            }
    }
    __syncthreads();
    if (kh == 0) {
#pragma unroll
        for (int ct = 4; ct < 8; ++ct)
#pragma unroll
            for (int r = 0; r < 16; ++r) {
                int qrow = (r & 3) + 8 * (r >> 2) + 4 * h;
                float li = __shfl(linv, qrow);
                float val = acc[ct][r] + mbuf[p * 4096 + qrow * 128 + (ct - 4) * 32 + row31];
                size_t idx = ((size_t)batch * NTOK + q0 + qrow) * CH + ct * 32 + row31;
                out[idx] = gm * (val * li) + x[idx];
            }
    }
}

// ---------------------------------------------------------------------------
extern "C" void kernel_launch(void* const* d_in, const int* in_sizes, int n_in,
                              void* d_out, int out_size, void* d_ws, size_t ws_size,
                              hipStream_t stream) {
    const float* x  = (const float*)d_in[0];
    const float* kf = (const float*)d_in[1];
    const float* kg = (const float*)d_in[2];
    const float* kh = (const float*)d_in[3];
    const float* bf = (const float*)d_in[4];
    const float* bg = (const float*)d_in[5];
    const float* bh = (const float*)d_in[6];
    const float* gm = (const float*)d_in[7];
    float* out = (float*)d_out;

    char* ws = (char*)d_ws;
    ushort* wfT = (ushort*)(ws);                       //  16 KB
    ushort* wgT = (ushort*)(ws + 16384);               //  16 KB
    ushort* whT = (ushort*)(ws + 32768);               // 128 KB
    ushort* fo  = (ushort*)(ws + 163840);              //   2 MB
    ushort* go  = (ushort*)(ws + 163840 + 2097152);    //   2 MB
    ushort* hT  = (ushort*)(ws + 163840 + 4194304);    //  16 MB

    hipLaunchKernelGGL(prep_weights, dim3(40), dim3(256), 0, stream, kf, kg, kh, wfT, wgT, whT);
    hipLaunchKernelGGL(proj_all, dim3(512), dim3(512), 0, stream,
                       x, wfT, wgT, whT, bf, bg, bh, fo, go, hT);
    hipLaunchKernelGGL(flash_attn, dim3(256), dim3(512), 0, stream, fo, go, hT, x, gm, out);
}

// Round 15
// 154.852 us; speedup vs baseline: 1.0188x; 1.0188x over previous
//
#include <hip/hip_runtime.h>
#include <hip/hip_bf16.h>

#define BATCH 8
#define NTOK 4096      // H*W per batch
#define CH 256
#define CF 32
#define KVBLK 128
#define NITER (NTOK / KVBLK)

typedef float v4f __attribute__((ext_vector_type(4)));
typedef float v16f __attribute__((ext_vector_type(16)));
typedef short v8s __attribute__((ext_vector_type(8)));

static __device__ __forceinline__ ushort f2bf(float f) {
    union { float f; uint u; } v; v.f = f;
    uint u = v.u;
    uint r = (u + 0x7fffu + ((u >> 16) & 1u)) >> 16;   // round-nearest-even
    return (ushort)r;
}

static __device__ __forceinline__ uint cvt_pk(float lo, float hi) {
    uint r;
    asm("v_cvt_pk_bf16_f32 %0, %1, %2" : "=v"(r) : "v"(lo), "v"(hi));
    return r;
}

// two-output lane swap across lane<32 / lane>=32
static __device__ __forceinline__ void plswap(uint& a, uint& b) {
    asm("v_permlane32_swap_b32 %0, %1" : "+v"(a), "+v"(b));
}

static __device__ __forceinline__ void gload16(const void* g, void* l) {
    __builtin_amdgcn_global_load_lds(
        (const __attribute__((address_space(1))) unsigned int*)g,
        (__attribute__((address_space(3))) unsigned int*)l, 16, 0, 0);
}

#define MFMA16(a, b, c) __builtin_amdgcn_mfma_f32_16x16x32_bf16(a, b, c, 0, 0, 0)
#define MFMA32(a, b, c) __builtin_amdgcn_mfma_f32_32x32x16_bf16(a, b, c, 0, 0, 0)

// ---------------------------------------------------------------------------
// Kernel 1: transpose + cast weights to bf16 via LDS tiles (coalesced both ways)
// ---------------------------------------------------------------------------
__global__ __launch_bounds__(256) void prep_weights(
    const float* __restrict__ kf, const float* __restrict__ kg,
    const float* __restrict__ kh,
    ushort* __restrict__ wfT, ushort* __restrict__ wgT, ushort* __restrict__ whT) {
    __shared__ float tile[64][33];
    int bid = blockIdx.x;
    const float* src; ushort* dst; int cols, k0, c0;
    if (bid < 32)      { src = kh; dst = whT; cols = 256; k0 = (bid >> 3) * 64; c0 = (bid & 7) * 32; }
    else if (bid < 36) { src = kf; dst = wfT; cols = 32;  k0 = (bid - 32) * 64; c0 = 0; }
    else               { src = kg; dst = wgT; cols = 32;  k0 = (bid - 36) * 64; c0 = 0; }
    int t = threadIdx.x;
    int kr = t >> 2, cb = (t & 3) * 8;
#pragma unroll
    for (int j = 0; j < 8; ++j) tile[kr][cb + j] = src[(size_t)(k0 + kr) * cols + c0 + cb + j];
    __syncthreads();
    int c = t >> 3, kc = (t & 7) * 8;
    ushort tmp[8];
#pragma unroll
    for (int j = 0; j < 8; ++j) tmp[j] = f2bf(tile[kc + j][c]);
    *(uint4*)(dst + (size_t)(c0 + c) * CH + k0 + kc) = *(uint4*)tmp;
}

// ---------------------------------------------------------------------------
// Kernel 2: fused projections (f, g, hT) — one x read; weights pipelined 1 step.
// (R13 version: simple scalar epilogue — the LDS-bounce variant measured slower.)
// ---------------------------------------------------------------------------
__global__ __launch_bounds__(512) void proj_all(
    const float* __restrict__ x, const ushort* __restrict__ wfT,
    const ushort* __restrict__ wgT, const ushort* __restrict__ whT,
    const float* __restrict__ bf, const float* __restrict__ bg,
    const float* __restrict__ bh,
    ushort* __restrict__ fo, ushort* __restrict__ go, ushort* __restrict__ hT) {
    __shared__ __align__(16) ushort xl[64 * 256];   // 32 KB, 16B-chunk swizzle ^(n&7)
    int tid = threadIdx.x;
    int lane = tid & 63, w = tid >> 6;
    int row = lane & 15, g4 = lane >> 4;
    int n0 = blockIdx.x * 64;

#pragma unroll
    for (int i = 0; i < 4; ++i) {
        int id = i * 512 + tid;          // 2048 chunks of 16 B
        int n = id >> 5, cc = id & 31;
        const float* xp = x + (size_t)(n0 + n) * CH + cc * 8;
        float4 a0 = ((const float4*)xp)[0], a1 = ((const float4*)xp)[1];
        uint4 pv;
        pv.x = cvt_pk(a0.x, a0.y); pv.y = cvt_pk(a0.z, a0.w);
        pv.z = cvt_pk(a1.x, a1.y); pv.w = cvt_pk(a1.z, a1.w);
        *(uint4*)((char*)xl + n * 512 + ((cc ^ (n & 7)) << 4)) = pv;
    }

    int c0 = w * 32;
    int myNt = w & 3;
    const ushort* wpT = (w < 4) ? wfT : wgT;

    // prefetch ks=0 weight fragments (L2)
    v8s wh0 = *(const v8s*)(whT + (size_t)(c0 + row) * CH + g4 * 8);
    v8s wh1 = *(const v8s*)(whT + (size_t)(c0 + 16 + row) * CH + g4 * 8);
    v8s wp0 = *(const v8s*)(wpT + (size_t)row * CH + g4 * 8);
    v8s wp1 = *(const v8s*)(wpT + (size_t)(16 + row) * CH + g4 * 8);

    __syncthreads();

    v4f acch[2][4] = {};
    v4f accp[2] = {};
    for (int ks = 0; ks < 8; ++ks) {
        v8s nh0 = {}, nh1 = {}, np0 = {}, np1 = {};
        if (ks < 7) {
            int kk = (ks + 1) * 32 + g4 * 8;
            nh0 = *(const v8s*)(whT + (size_t)(c0 + row) * CH + kk);
            nh1 = *(const v8s*)(whT + (size_t)(c0 + 16 + row) * CH + kk);
            np0 = *(const v8s*)(wpT + (size_t)row * CH + kk);
            np1 = *(const v8s*)(wpT + (size_t)(16 + row) * CH + kk);
        }
        v8s xf[4];
#pragma unroll
        for (int nt = 0; nt < 4; ++nt) {
            int n = nt * 16 + row;
            int ch = (ks * 4 + g4) ^ (n & 7);
            xf[nt] = *(const v8s*)((char*)xl + n * 512 + (ch << 4));
        }
#pragma unroll
        for (int nt = 0; nt < 4; ++nt) {
            acch[0][nt] = MFMA16(wh0, xf[nt], acch[0][nt]);
            acch[1][nt] = MFMA16(wh1, xf[nt], acch[1][nt]);
        }
        accp[0] = MFMA16(xf[myNt], wp0, accp[0]);
        accp[1] = MFMA16(xf[myNt], wp1, accp[1]);
        wh0 = nh0; wh1 = nh1; wp0 = np0; wp1 = np1;
    }

    int batch = n0 >> 12;
    int nn0 = n0 & (NTOK - 1);
    ushort* hTb = hT + (size_t)batch * CH * NTOK;
#pragma unroll
    for (int ct = 0; ct < 2; ++ct)
#pragma unroll
        for (int r = 0; r < 4; ++r) {
            int c = c0 + ct * 16 + g4 * 4 + r;
            float bias = bh[c];
#pragma unroll
            for (int nt = 0; nt < 4; ++nt)
                hTb[(size_t)c * NTOK + nn0 + nt * 16 + row] = f2bf(acch[ct][nt][r] + bias);
        }
    const float* bp = (w < 4) ? bf : bg;
    ushort* po = (w < 4) ? fo : go;
#pragma unroll
    for (int ct = 0; ct < 2; ++ct)
#pragma unroll
        for (int r = 0; r < 4; ++r) {
            int n = n0 + myNt * 16 + g4 * 4 + r;
            int cf = ct * 16 + row;
            po[(size_t)n * CF + cf] = f2bf(accp[ct][r] + bp[cf]);
        }
}

// ---------------------------------------------------------------------------
// Kernel 3: flash attention.  4-wave blocks (2 qg x 2 kh), 64 q per block;
// grid 512 = 2 blocks/CU -> independent barrier groups overlap stalls.
// Single-buffered V (64 KB, 16-chunk swizzle = conflict-free); K in registers;
// no-max softmax P = exp(s-24); in-register P pack; kh merge via LDS epilogue.
// ---------------------------------------------------------------------------
__global__ __launch_bounds__(256, 2) void flash_attn(
    const ushort* __restrict__ fbuf, const ushort* __restrict__ gbuf,
    const ushort* __restrict__ hT, const float* __restrict__ x,
    const float* __restrict__ gamma, float* __restrict__ out) {
    __shared__ __align__(16) ushort lds_v[32768];   // 64 KB (256c x 128k)
    __shared__ float lsx[2][32];                    // [qg][q] lsum exchange

    int tid = threadIdx.x;
    int lane = tid & 63, w = tid >> 6;
    int row31 = lane & 31, h = lane >> 5;
    int batch = blockIdx.x & 7;
    int qg = w >> 1, kh = w & 1;
    int q0 = (blockIdx.x >> 3) * 64 + qg * 32;

    const ushort* fB = fbuf + (size_t)batch * NTOK * CF;
    const ushort* gB = gbuf + (size_t)batch * NTOK * CF;
    const ushort* hB = hT + (size_t)batch * CH * NTOK;

    // ---- V staging: 4096 chunks of 16B; 256 thr x 16 chunks ----
    int crow = tid >> 4;                                  // 0..15
    int koffe = ((tid & 15) ^ crow) << 3;                 // pre-swizzled key offset
    const ushort* vpb = hB + (size_t)crow * NTOK + koffe; // + i*16*NTOK per chunk

#define STAGE() do {                                                       \
        _Pragma("unroll")                                                  \
        for (int i_ = 0; i_ < 16; ++i_)                                    \
            gload16(vpb + (size_t)(i_ * 16) * NTOK,                        \
                    (char*)&lds_v[0] + (i_ * 256 + tid) * 16);             \
    } while (0)

    // K A-frag source: rows kh*64 + kt*32 + row31, cols h*8 (+16 for cf-half 1)
    const ushort* kp = fB + (size_t)(kh * 64 + row31) * CF + h * 8;

    // hoisted V LDS offsets: ch = kh*8 + (kt*2+j)*2 + h, phys = ch ^ (row31&15)
    int voff[2][2];
#pragma unroll
    for (int kt = 0; kt < 2; ++kt)
#pragma unroll
        for (int j = 0; j < 2; ++j) {
            int ch = kh * 8 + (kt * 2 + j) * 2 + h;
            voff[kt][j] = row31 * 256 + ((ch ^ (row31 & 15)) << 4);
        }

    // Q^T B-frags
    v8s bq[2];
    bq[0] = *(const v8s*)(gB + (size_t)(q0 + row31) * CF + h * 8);
    bq[1] = *(const v8s*)(gB + (size_t)(q0 + row31) * CF + 16 + h * 8);

    float lsum = 0.f;
    v16f acc[8] = {};   // O partial: 32 q x 256 c
    const v16f z16 = {};

    // prologue: V(0) staged + K(0) loaded, drained
    v8s k00 = *(const v8s*)kp;
    v8s k01 = *(const v8s*)(kp + 16);
    v8s k10 = *(const v8s*)(kp + 32 * CF);
    v8s k11 = *(const v8s*)(kp + 32 * CF + 16);
    kp += KVBLK * CF;
    STAGE(); vpb += KVBLK;
    asm volatile("s_waitcnt vmcnt(0)" ::: "memory");
    __builtin_amdgcn_s_barrier();

    for (int t = 0; t < NITER; ++t) {
        const char* vb = (const char*)&lds_v[0];

        // ---- S = K_half * Q^T : 2 key-tiles of 32 (register K) ----
        v16f s0, s1;
        s0 = MFMA32(k00, bq[0], z16); s0 = MFMA32(k01, bq[1], s0);
        s1 = MFMA32(k10, bq[0], z16); s1 = MFMA32(k11, bq[1], s1);

        // ---- no-max softmax ----
        float psum = 0.f;
#pragma unroll
        for (int r = 0; r < 16; ++r) {
            s0[r] = __builtin_amdgcn_exp2f(s0[r] * 1.44269504f - 34.6246924f);
            s1[r] = __builtin_amdgcn_exp2f(s1[r] * 1.44269504f - 34.6246924f);
            psum += s0[r] + s1[r];
        }
        psum += __shfl_xor(psum, 32);
        lsum += psum;

        // ---- pack + PV, per key-tile x j-half ----
        __builtin_amdgcn_s_setprio(1);
#pragma unroll
        for (int kt = 0; kt < 2; ++kt)
#pragma unroll
            for (int j = 0; j < 2; ++j) {
                int R = j * 8;
                uint a0, a1, b0, b1;
                if (kt == 0) {
                    a0 = cvt_pk(s0[R + 0], s0[R + 1]); a1 = cvt_pk(s0[R + 2], s0[R + 3]);
                    b0 = cvt_pk(s0[R + 4], s0[R + 5]); b1 = cvt_pk(s0[R + 6], s0[R + 7]);
                } else {
                    a0 = cvt_pk(s1[R + 0], s1[R + 1]); a1 = cvt_pk(s1[R + 2], s1[R + 3]);
                    b0 = cvt_pk(s1[R + 4], s1[R + 5]); b1 = cvt_pk(s1[R + 6], s1[R + 7]);
                }
                plswap(a0, b0);
                plswap(a1, b1);
                union { v8s v; uint u[4]; } pu;
                pu.u[0] = a0; pu.u[1] = a1; pu.u[2] = b0; pu.u[3] = b1;
#pragma unroll
                for (int ct = 0; ct < 8; ++ct) {
                    v8s bv = *(const v8s*)(vb + voff[kt][j] + ct * 8192);
                    acc[ct] = MFMA32(pu.v, bv, acc[ct]);
                }
            }
        __builtin_amdgcn_s_setprio(0);

        // ---- restage (single buffer): WAR barrier, stage t+1, drain ----
        __builtin_amdgcn_s_barrier();           // everyone done reading V(t)
        if (t + 1 < NITER) {
            STAGE(); vpb += KVBLK;
            v8s n00 = *(const v8s*)kp;
            v8s n01 = *(const v8s*)(kp + 16);
            v8s n10 = *(const v8s*)(kp + 32 * CF);
            v8s n11 = *(const v8s*)(kp + 32 * CF + 16);
            kp += KVBLK * CF;
            asm volatile("s_waitcnt vmcnt(0)" ::: "memory");
            k00 = n00; k01 = n01; k10 = n10; k11 = n11;
            __builtin_amdgcn_s_barrier();       // V(t+1) visible to all waves
        }
    }
#undef STAGE

    // ---- epilogue: merge kh pair (plain add), out = gamma*O/lsum + x ----
    __syncthreads();    // all waves done with lds_v before reuse as mbuf
    float gm = gamma[0];
    float* mbuf = (float*)&lds_v[0];   // 16384 floats
    int p = qg;
    if (kh == 1) {
        lsx[p][row31] = lsum;
#pragma unroll
        for (int ct = 0; ct < 4; ++ct)
#pragma unroll
            for (int r = 0; r < 16; ++r) {
                int qrow = (r & 3) + 8 * (r >> 2) + 4 * h;
                mbuf[p * 4096 + qrow * 128 + ct * 32 + row31] = acc[ct][r];
            }
    }
    __syncthreads();
    float linv = 0.f;
    if (kh == 0) {
        float ltot = lsum + lsx[p][row31];
        linv = 1.0f / ltot;
#pragma unroll
        for (int ct = 0; ct < 4; ++ct)
#pragma unroll
            for (int r = 0; r < 16; ++r) {
                int qrow = (r & 3) + 8 * (r >> 2) + 4 * h;
                float li = __shfl(linv, qrow);
                float val = acc[ct][r] + mbuf[p * 4096 + qrow * 128 + ct * 32 + row31];
                size_t idx = ((size_t)batch * NTOK + q0 + qrow) * CH + ct * 32 + row31;
                out[idx] = gm * (val * li) + x[idx];
            }
    }
    __syncthreads();
    if (kh == 1) {
#pragma unroll
        for (int ct = 4; ct < 8; ++ct)
#pragma unroll
            for (int r = 0; r < 16; ++r) {
                int qrow = (r & 3) + 8 * (r >> 2) + 4 * h;
                mbuf[p * 4096 + qrow * 128 + (ct - 4) * 32 + row31] = acc[ct][r];
            }
    }
    __syncthreads();
    if (kh == 0) {
#pragma unroll
        for (int ct = 4; ct < 8; ++ct)
#pragma unroll
            for (int r = 0; r < 16; ++r) {
                int qrow = (r & 3) + 8 * (r >> 2) + 4 * h;
                float li = __shfl(linv, qrow);
                float val = acc[ct][r] + mbuf[p * 4096 + qrow * 128 + (ct - 4) * 32 + row31];
                size_t idx = ((size_t)batch * NTOK + q0 + qrow) * CH + ct * 32 + row31;
                out[idx] = gm * (val * li) + x[idx];
            }
    }
}

// ---------------------------------------------------------------------------
extern "C" void kernel_launch(void* const* d_in, const int* in_sizes, int n_in,
                              void* d_out, int out_size, void* d_ws, size_t ws_size,
                              hipStream_t stream) {
    const float* x  = (const float*)d_in[0];
    const float* kf = (const float*)d_in[1];
    const float* kg = (const float*)d_in[2];
    const float* kh = (const float*)d_in[3];
    const float* bf = (const float*)d_in[4];
    const float* bg = (const float*)d_in[5];
    const float* bh = (const float*)d_in[6];
    const float* gm = (const float*)d_in[7];
    float* out = (float*)d_out;

    char* ws = (char*)d_ws;
    ushort* wfT = (ushort*)(ws);                       //  16 KB
    ushort* wgT = (ushort*)(ws + 16384);               //  16 KB
    ushort* whT = (ushort*)(ws + 32768);               // 128 KB
    ushort* fo  = (ushort*)(ws + 163840);              //   2 MB
    ushort* go  = (ushort*)(ws + 163840 + 2097152);    //   2 MB
    ushort* hT  = (ushort*)(ws + 163840 + 4194304);    //  16 MB

    hipLaunchKernelGGL(prep_weights, dim3(40), dim3(256), 0, stream, kf, kg, kh, wfT, wgT, whT);
    hipLaunchKernelGGL(proj_all, dim3(512), dim3(512), 0, stream,
                       x, wfT, wgT, whT, bf, bg, bh, fo, go, hT);
    hipLaunchKernelGGL(flash_attn, dim3(512), dim3(256), 0, stream, fo, go, hT, x, gm, out);
}

// Round 16
// 127.322 us; speedup vs baseline: 1.2391x; 1.2162x over previous
//
#include <hip/hip_runtime.h>
#include <hip/hip_bf16.h>

#define BATCH 8
#define NTOK 4096      // H*W per batch
#define CH 256
#define CF 32
#define KVBLK 128
#define NITER (NTOK / KVBLK)

typedef float v4f __attribute__((ext_vector_type(4)));
typedef float v16f __attribute__((ext_vector_type(16)));
typedef short v8s __attribute__((ext_vector_type(8)));

static __device__ __forceinline__ ushort f2bf(float f) {
    union { float f; uint u; } v; v.f = f;
    uint u = v.u;
    uint r = (u + 0x7fffu + ((u >> 16) & 1u)) >> 16;   // round-nearest-even
    return (ushort)r;
}

static __device__ __forceinline__ uint cvt_pk(float lo, float hi) {
    uint r;
    asm("v_cvt_pk_bf16_f32 %0, %1, %2" : "=v"(r) : "v"(lo), "v"(hi));
    return r;
}

// two-output lane swap across lane<32 / lane>=32
static __device__ __forceinline__ void plswap(uint& a, uint& b) {
    asm("v_permlane32_swap_b32 %0, %1" : "+v"(a), "+v"(b));
}

static __device__ __forceinline__ void gload16(const void* g, void* l) {
    __builtin_amdgcn_global_load_lds(
        (const __attribute__((address_space(1))) unsigned int*)g,
        (__attribute__((address_space(3))) unsigned int*)l, 16, 0, 0);
}

#define MFMA16(a, b, c) __builtin_amdgcn_mfma_f32_16x16x32_bf16(a, b, c, 0, 0, 0)
#define MFMA32(a, b, c) __builtin_amdgcn_mfma_f32_32x32x16_bf16(a, b, c, 0, 0, 0)

// ---------------------------------------------------------------------------
// Kernel 1: transpose + cast weights to bf16 via LDS tiles (coalesced both ways)
// ---------------------------------------------------------------------------
__global__ __launch_bounds__(256) void prep_weights(
    const float* __restrict__ kf, const float* __restrict__ kg,
    const float* __restrict__ kh,
    ushort* __restrict__ wfT, ushort* __restrict__ wgT, ushort* __restrict__ whT) {
    __shared__ float tile[64][33];
    int bid = blockIdx.x;
    const float* src; ushort* dst; int cols, k0, c0;
    if (bid < 32)      { src = kh; dst = whT; cols = 256; k0 = (bid >> 3) * 64; c0 = (bid & 7) * 32; }
    else if (bid < 36) { src = kf; dst = wfT; cols = 32;  k0 = (bid - 32) * 64; c0 = 0; }
    else               { src = kg; dst = wgT; cols = 32;  k0 = (bid - 36) * 64; c0 = 0; }
    int t = threadIdx.x;
    int kr = t >> 2, cb = (t & 3) * 8;
#pragma unroll
    for (int j = 0; j < 8; ++j) tile[kr][cb + j] = src[(size_t)(k0 + kr) * cols + c0 + cb + j];
    __syncthreads();
    int c = t >> 3, kc = (t & 7) * 8;
    ushort tmp[8];
#pragma unroll
    for (int j = 0; j < 8; ++j) tmp[j] = f2bf(tile[kc + j][c]);
    *(uint4*)(dst + (size_t)(c0 + c) * CH + k0 + kc) = *(uint4*)tmp;
}

// ---------------------------------------------------------------------------
// Kernel 2: proj_fgx — f/g projections (weights LDS-staged) + XT transpose.
// 512 blocks x 256 thr (4 waves); block = 64 n rows.  One x read total.
// ---------------------------------------------------------------------------
__global__ __launch_bounds__(256) void proj_fgx(
    const float* __restrict__ x, const ushort* __restrict__ wfT,
    const ushort* __restrict__ wgT, const float* __restrict__ bf,
    const float* __restrict__ bg,
    ushort* __restrict__ fo, ushort* __restrict__ go, ushort* __restrict__ XT) {
    __shared__ __align__(16) ushort xl[64 * 256];       // 32 KB, chunk swz ^(n&7)
    __shared__ __align__(16) ushort wl[2][32 * 256];    // 32 KB, chunk swz ^(r&7)
    int tid = threadIdx.x;
    int lane = tid & 63, w = tid >> 6;
    int row15 = lane & 15, g4 = lane >> 4;
    int n0 = blockIdx.x * 64;
    int batch = n0 >> 12, nn0 = n0 & (NTOK - 1);

    // stage weights (gload16, pre-swizzled source, linear dest)
#pragma unroll
    for (int i = 0; i < 8; ++i) {
        int id = i * 256 + tid;          // 2048 chunks
        int sel = id >> 10, r = (id >> 5) & 31, s = id & 31;
        const ushort* src = (sel ? wgT : wfT) + r * CH + ((s ^ (r & 7)) << 3);
        gload16(src, (char*)&wl[0][0] + id * 16);
    }
    // stage x -> bf16 swizzled LDS
#pragma unroll
    for (int i = 0; i < 8; ++i) {
        int id = i * 256 + tid;          // 2048 chunks
        int n = id >> 5, cc = id & 31;
        const float* xp = x + (size_t)(n0 + n) * CH + cc * 8;
        float4 a0 = ((const float4*)xp)[0], a1 = ((const float4*)xp)[1];
        uint4 pv;
        pv.x = cvt_pk(a0.x, a0.y); pv.y = cvt_pk(a0.z, a0.w);
        pv.z = cvt_pk(a1.x, a1.y); pv.w = cvt_pk(a1.z, a1.w);
        *(uint4*)((char*)xl + n * 512 + ((cc ^ (n & 7)) << 4)) = pv;
    }
    asm volatile("s_waitcnt vmcnt(0)" ::: "memory");
    __syncthreads();

    // compute f,g: wave w owns n rows w*16..+16
    v4f accF[2] = {}, accG[2] = {};
    int nrow = w * 16 + row15;
    for (int ks = 0; ks < 8; ++ks) {
        v8s xf = *(const v8s*)((char*)xl + nrow * 512 + (((ks * 4 + g4) ^ (nrow & 7)) << 4));
#pragma unroll
        for (int ct = 0; ct < 2; ++ct) {
            int wr = ct * 16 + row15;
            int wb = wr * 512 + (((ks * 4 + g4) ^ (wr & 7)) << 4);
            v8s bwf = *(const v8s*)((char*)&wl[0][0] + wb);
            v8s bwg = *(const v8s*)((char*)&wl[1][0] + wb);
            accF[ct] = MFMA16(xf, bwf, accF[ct]);
            accG[ct] = MFMA16(xf, bwg, accG[ct]);
        }
    }
#pragma unroll
    for (int ct = 0; ct < 2; ++ct)
#pragma unroll
        for (int r = 0; r < 4; ++r) {
            int n = n0 + w * 16 + g4 * 4 + r;
            int cf = ct * 16 + row15;
            fo[(size_t)n * CF + cf] = f2bf(accF[ct][r] + bf[cf]);
            go[(size_t)n * CF + cf] = f2bf(accG[ct][r] + bg[cf]);
        }

    // XT write: thread (c=tid, nch=i): gather 8 n, 16B store to XT[c][nn0+i*8]
    ushort* XTb = XT + (size_t)batch * CH * NTOK;
    int c = tid;
#pragma unroll
    for (int i = 0; i < 8; ++i) {
        ushort tmp[8];
#pragma unroll
        for (int j = 0; j < 8; ++j) {
            int row = i * 8 + j;
            int chunk = (c >> 3) ^ j;
            tmp[j] = xl[row * 256 + chunk * 8 + (c & 7)];
        }
        *(uint4*)(XTb + (size_t)c * NTOK + nn0 + i * 8) = *(uint4*)tmp;
    }
}

// ---------------------------------------------------------------------------
// Kernel 3: flash attention (R14 structure; V = XT).  KVBLK=128, 32 iters.
// 512 thr = 8 waves = 4 qg(32q) x 2 kh(64key); grid 256 (1 block/CU).
// Writes PX = P*X partials (bf16) + lsum; h-projection deferred to gemm_h.
// ---------------------------------------------------------------------------
__global__ __launch_bounds__(512, 1) void flash_attn(
    const ushort* __restrict__ fbuf, const ushort* __restrict__ gbuf,
    const ushort* __restrict__ XT,
    ushort* __restrict__ PX, float* __restrict__ lsw) {
    __shared__ __align__(16) ushort lds_v[2][32768];   // 128 KB (256c x 128k each)
    __shared__ float lsx[4][32];                       // pair lsum exchange

    int tid = threadIdx.x;
    int lane = tid & 63, w = tid >> 6;
    int row31 = lane & 31, h = lane >> 5;
    int batch = blockIdx.x & 7;
    int qg = w >> 1, kh = w & 1;
    int q0 = (blockIdx.x >> 3) * 128 + qg * 32;

    const ushort* fB = fbuf + (size_t)batch * NTOK * CF;
    const ushort* gB = gbuf + (size_t)batch * NTOK * CF;
    const ushort* vB = XT + (size_t)batch * CH * NTOK;

    // ---- V staging: 4096 chunks of 16B; thread covers 8 ----
    int crow = tid >> 4;                                  // 0..31
    int koffe = ((tid & 15) ^ (crow & 15)) << 3;          // pre-swizzled key offset
    const ushort* vpb = vB + (size_t)crow * NTOK + koffe;

#define STAGE(buf) do {                                                    \
        _Pragma("unroll")                                                  \
        for (int i_ = 0; i_ < 8; ++i_)                                     \
            gload16(vpb + (size_t)(i_ * 32) * NTOK,                        \
                    (char*)&lds_v[buf][0] + (i_ * 512 + tid) * 16);        \
    } while (0)

    const ushort* kp = fB + (size_t)(kh * 64 + row31) * CF + h * 8;

    int voff[2][2];
#pragma unroll
    for (int kt = 0; kt < 2; ++kt)
#pragma unroll
        for (int j = 0; j < 2; ++j) {
            int ch = kh * 8 + (kt * 2 + j) * 2 + h;
            voff[kt][j] = row31 * 256 + ((ch ^ (row31 & 15)) << 4);
        }

    v8s bq[2];
    bq[0] = *(const v8s*)(gB + (size_t)(q0 + row31) * CF + h * 8);
    bq[1] = *(const v8s*)(gB + (size_t)(q0 + row31) * CF + 16 + h * 8);

    float lsum = 0.f;
    v16f acc[8] = {};   // PX partial: 32 q x 256 c
    const v16f z16 = {};

    v8s k00 = *(const v8s*)kp;
    v8s k01 = *(const v8s*)(kp + 16);
    v8s k10 = *(const v8s*)(kp + 32 * CF);
    v8s k11 = *(const v8s*)(kp + 32 * CF + 16);
    kp += KVBLK * CF;
    STAGE(0); vpb += KVBLK;

    for (int t = 0; t < NITER; ++t) {
        int cur = t & 1;
        __builtin_amdgcn_s_barrier();           // B1: WAR-protect buf being restaged
        v8s n00 = {}, n01 = {}, n10 = {}, n11 = {};
        if (t + 1 < NITER) {
            STAGE(cur ^ 1); vpb += KVBLK;
            n00 = *(const v8s*)kp;
            n01 = *(const v8s*)(kp + 16);
            n10 = *(const v8s*)(kp + 32 * CF);
            n11 = *(const v8s*)(kp + 32 * CF + 16);
            kp += KVBLK * CF;
            asm volatile("s_waitcnt vmcnt(12)" ::: "memory");  // tile-t landed
        } else {
            asm volatile("s_waitcnt vmcnt(0)" ::: "memory");
        }
        __builtin_amdgcn_s_barrier();           // B2: all waves' tile-t data ready

        const char* vb = (const char*)&lds_v[cur][0];

        v16f s0, s1;
        s0 = MFMA32(k00, bq[0], z16); s0 = MFMA32(k01, bq[1], s0);
        s1 = MFMA32(k10, bq[0], z16); s1 = MFMA32(k11, bq[1], s1);

        float psum = 0.f;
#pragma unroll
        for (int r = 0; r < 16; ++r) {
            s0[r] = __builtin_amdgcn_exp2f(s0[r] * 1.44269504f - 34.6246924f);
            s1[r] = __builtin_amdgcn_exp2f(s1[r] * 1.44269504f - 34.6246924f);
            psum += s0[r] + s1[r];
        }
        psum += __shfl_xor(psum, 32);
        lsum += psum;

        __builtin_amdgcn_s_setprio(1);
#pragma unroll
        for (int kt = 0; kt < 2; ++kt)
#pragma unroll
            for (int j = 0; j < 2; ++j) {
                int R = j * 8;
                uint a0, a1, b0, b1;
                if (kt == 0) {
                    a0 = cvt_pk(s0[R + 0], s0[R + 1]); a1 = cvt_pk(s0[R + 2], s0[R + 3]);
                    b0 = cvt_pk(s0[R + 4], s0[R + 5]); b1 = cvt_pk(s0[R + 6], s0[R + 7]);
                } else {
                    a0 = cvt_pk(s1[R + 0], s1[R + 1]); a1 = cvt_pk(s1[R + 2], s1[R + 3]);
                    b0 = cvt_pk(s1[R + 4], s1[R + 5]); b1 = cvt_pk(s1[R + 6], s1[R + 7]);
                }
                plswap(a0, b0);
                plswap(a1, b1);
                union { v8s v; uint u[4]; } pu;
                pu.u[0] = a0; pu.u[1] = a1; pu.u[2] = b0; pu.u[3] = b1;
#pragma unroll
                for (int ct = 0; ct < 8; ++ct) {
                    v8s bv = *(const v8s*)(vb + voff[kt][j] + ct * 8192);
                    acc[ct] = MFMA32(pu.v, bv, acc[ct]);
                }
            }
        __builtin_amdgcn_s_setprio(0);
        k00 = n00; k01 = n01; k10 = n10; k11 = n11;
    }
#undef STAGE

    // ---- epilogue: merge kh pair (plain add), store PX bf16 + lsum ----
    float* mbuf = (float*)&lds_v[0][0];
    int p = qg;
    if (kh == 1) {
        lsx[p][row31] = lsum;
#pragma unroll
        for (int ct = 0; ct < 4; ++ct)
#pragma unroll
            for (int r = 0; r < 16; ++r) {
                int qrow = (r & 3) + 8 * (r >> 2) + 4 * h;
                mbuf[p * 4096 + qrow * 128 + ct * 32 + row31] = acc[ct][r];
            }
    }
    __syncthreads();
    if (kh == 0) {
        float ltot = lsum + lsx[p][row31];
        if (h == 0) lsw[batch * NTOK + q0 + row31] = ltot;
#pragma unroll
        for (int ct = 0; ct < 4; ++ct)
#pragma unroll
            for (int r = 0; r < 16; ++r) {
                int qrow = (r & 3) + 8 * (r >> 2) + 4 * h;
                float val = acc[ct][r] + mbuf[p * 4096 + qrow * 128 + ct * 32 + row31];
                PX[((size_t)batch * NTOK + q0 + qrow) * CH + ct * 32 + row31] = f2bf(val);
            }
    }
    __syncthreads();
    if (kh == 1) {
#pragma unroll
        for (int ct = 4; ct < 8; ++ct)
#pragma unroll
            for (int r = 0; r < 16; ++r) {
                int qrow = (r & 3) + 8 * (r >> 2) + 4 * h;
                mbuf[p * 4096 + qrow * 128 + (ct - 4) * 32 + row31] = acc[ct][r];
            }
    }
    __syncthreads();
    if (kh == 0) {
#pragma unroll
        for (int ct = 4; ct < 8; ++ct)
#pragma unroll
            for (int r = 0; r < 16; ++r) {
                int qrow = (r & 3) + 8 * (r >> 2) + 4 * h;
                float val = acc[ct][r] + mbuf[p * 4096 + qrow * 128 + (ct - 4) * 32 + row31];
                PX[((size_t)batch * NTOK + q0 + qrow) * CH + ct * 32 + row31] = f2bf(val);
            }
    }
}

// ---------------------------------------------------------------------------
// Kernel 4: gemm_h — out = gamma*(PX*Wh)/lsum + gamma*bh + x.
// grid (512 n-tiles, 4 c-tiles) x 256 thr; both operands LDS-staged.
// ---------------------------------------------------------------------------
__global__ __launch_bounds__(256) void gemm_h(
    const ushort* __restrict__ PX, const ushort* __restrict__ whT,
    const float* __restrict__ lsw, const float* __restrict__ bh,
    const float* __restrict__ x, const float* __restrict__ gamma,
    float* __restrict__ out) {
    __shared__ __align__(16) ushort pxl[64 * 256];   // 32 KB, chunk swz ^(n&7)
    __shared__ __align__(16) ushort wll[64 * 256];   // 32 KB, chunk swz ^(c&7)
    int tid = threadIdx.x;
    int lane = tid & 63, w = tid >> 6;
    int row15 = lane & 15, g4 = lane >> 4;
    int n0 = blockIdx.x * 64, c0 = blockIdx.y * 64;

#pragma unroll
    for (int i = 0; i < 8; ++i) {
        int id = i * 256 + tid;
        int n = id >> 5, s = id & 31;
        gload16(PX + (size_t)(n0 + n) * CH + ((s ^ (n & 7)) << 3),
                (char*)pxl + id * 16);
    }
#pragma unroll
    for (int i = 0; i < 8; ++i) {
        int id = i * 256 + tid;
        int c = id >> 5, s = id & 31;
        gload16(whT + (size_t)(c0 + c) * CH + ((s ^ (c & 7)) << 3),
                (char*)wll + id * 16);
    }
    asm volatile("s_waitcnt vmcnt(0)" ::: "memory");
    __syncthreads();

    v4f acc[4] = {};
    int wr = w * 16 + row15;    // c-row within 64
    for (int ks = 0; ks < 8; ++ks) {
        v8s bw = *(const v8s*)((char*)wll + wr * 512 + (((ks * 4 + g4) ^ (wr & 7)) << 4));
#pragma unroll
        for (int nt = 0; nt < 4; ++nt) {
            int nr = nt * 16 + row15;
            v8s af = *(const v8s*)((char*)pxl + nr * 512 + (((ks * 4 + g4) ^ (nr & 7)) << 4));
            acc[nt] = MFMA16(af, bw, acc[nt]);
        }
    }

    float gm = gamma[0];
    int c = c0 + w * 16 + row15;
    float bhc = gm * bh[c];
#pragma unroll
    for (int nt = 0; nt < 4; ++nt)
#pragma unroll
        for (int r = 0; r < 4; ++r) {
            int n = n0 + nt * 16 + g4 * 4 + r;
            float li = 1.0f / lsw[n];
            size_t idx = (size_t)n * CH + c;
            out[idx] = gm * acc[nt][r] * li + bhc + x[idx];
        }
}

// ---------------------------------------------------------------------------
extern "C" void kernel_launch(void* const* d_in, const int* in_sizes, int n_in,
                              void* d_out, int out_size, void* d_ws, size_t ws_size,
                              hipStream_t stream) {
    const float* x  = (const float*)d_in[0];
    const float* kf = (const float*)d_in[1];
    const float* kg = (const float*)d_in[2];
    const float* kh = (const float*)d_in[3];
    const float* bf = (const float*)d_in[4];
    const float* bg = (const float*)d_in[5];
    const float* bh = (const float*)d_in[6];
    const float* gm = (const float*)d_in[7];
    float* out = (float*)d_out;

    char* ws = (char*)d_ws;
    ushort* wfT = (ushort*)(ws);                       //  16 KB
    ushort* wgT = (ushort*)(ws + 16384);               //  16 KB
    ushort* whT = (ushort*)(ws + 32768);               // 128 KB
    ushort* fo  = (ushort*)(ws + 163840);              //   2 MB
    ushort* go  = (ushort*)(ws + 163840 + 2097152);    //   2 MB
    ushort* XT  = (ushort*)(ws + 4358144);             //  16 MB
    ushort* PX  = (ushort*)(ws + 4358144 + 16777216);  //  16 MB
    float*  lsw = (float* )(ws + 4358144 + 33554432);  // 128 KB
    // total ws use: ~38 MB

    hipLaunchKernelGGL(prep_weights, dim3(40), dim3(256), 0, stream, kf, kg, kh, wfT, wgT, whT);
    hipLaunchKernelGGL(proj_fgx, dim3(512), dim3(256), 0, stream,
                       x, wfT, wgT, bf, bg, fo, go, XT);
    hipLaunchKernelGGL(flash_attn, dim3(256), dim3(512), 0, stream, fo, go, XT, PX, lsw);
    hipLaunchKernelGGL(gemm_h, dim3(512, 4), dim3(256), 0, stream,
                       PX, whT, lsw, bh, x, gm, out);
}